// Round 3
// baseline (439.580 us; speedup 1.0000x reference)
//
#include <hip/hip_runtime.h>
#include <hip/hip_bf16.h>

#define FEAT   1024
#define HID    256
#define TSTEPS 24
#define NCLS   10

typedef unsigned int u32;
typedef unsigned long long u64;

// ---- workspace layout (float offsets) ----
constexpr int OFF_W1T  = 0;                    // [1024][256] fp32, f-major (W1 transposed)
constexpr int OFF_W2T  = OFF_W1T + FEAT*HID;   // [256][256]  fp32, f-major
constexpr int OFF_W3T  = OFF_W2T + HID*HID;    // [256][256]  fp32, f-major
constexpr int OFF_WLI  = OFF_W3T + HID*HID;    // [10][256]   fp32, plain copy
constexpr int OFF_B1   = OFF_WLI + NCLS*HID;
constexpr int OFF_B2   = OFF_B1 + HID;
constexpr int OFF_B3   = OFF_B2 + HID;
constexpr int OFF_FLAG = OFF_B3 + HID;         // u32: 1 = inputs bf16, 0 = fp32

// ---- LI readout linearized: vo_24 = sum_t coef[t] * (o3_t @ Wli^T).
// c_23 = 0; c_{u-1} = 0.8*c_u + 0.1*0.9^(23-u).
struct CoefT { float c[TSTEPS]; };
constexpr CoefT make_coef() {
    CoefT r{};
    double c = 0.0, p9 = 1.0;
    r.c[TSTEPS-1] = 0.0f;
    for (int u = TSTEPS-1; u > 0; u--) {
        c = 0.8 * c + 0.1 * p9;
        p9 *= 0.9;
        r.c[u-1] = (float)c;
    }
    return r;
}
__device__ constexpr CoefT COEF = make_coef();

// ---- dtype detector: fp32 data read as bf16 -> mantissa-as-exponent garbage.
__global__ void detect_dtype_k(const void* __restrict__ x, u32* __restrict__ flag) {
    __shared__ int bad;
    if (threadIdx.x == 0) bad = 0;
    __syncthreads();
    float v = __bfloat162float(((const __hip_bfloat16*)x)[threadIdx.x]);
    if (!(fabsf(v) < 100.0f)) atomicOr(&bad, 1);
    __syncthreads();
    if (threadIdx.x == 0) *flag = bad ? 0u : 1u;
}

__device__ __forceinline__ float rd_any(const void* p, int idx, u32 isbf) {
    return isbf ? __bfloat162float(((const __hip_bfloat16*)p)[idx])
                : ((const float*)p)[idx];
}

// ---- prep: COALESCED reads, scattered writes (stores don't stall) ----
__global__ void prep_weights_k(const void* W1, const void* W2, const void* W3,
                               const void* Wli, const void* b1, const void* b2,
                               const void* b3, float* __restrict__ ws) {
    const u32 isbf = ((const u32*)(ws + OFF_FLAG))[0];
    int id = blockIdx.x * 256 + threadIdx.x;
    if (id < FEAT*HID) {                 // read W1[h][f] contiguous; write W1T[f][h]
        int h = id >> 10, f = id & 1023;
        ws[OFF_W1T + f*HID + h] = rd_any(W1, id, isbf);
        return;
    }
    id -= FEAT*HID;
    if (id < HID*HID) {
        int h = id >> 8, f = id & 255;
        ws[OFF_W2T + f*HID + h] = rd_any(W2, id, isbf);
        return;
    }
    id -= HID*HID;
    if (id < HID*HID) {
        int h = id >> 8, f = id & 255;
        ws[OFF_W3T + f*HID + h] = rd_any(W3, id, isbf);
        return;
    }
    id -= HID*HID;
    if (id < NCLS*HID) { ws[OFF_WLI + id] = rd_any(Wli, id, isbf); return; }
    id -= NCLS*HID;
    if (id < HID) { ws[OFF_B1 + id] = rd_any(b1, id, isbf); return; }
    id -= HID;
    if (id < HID) { ws[OFF_B2 + id] = rd_any(b2, id, isbf); return; }
    id -= HID;
    if (id < HID) { ws[OFF_B3 + id] = rd_any(b3, id, isbf); return; }
}

// 4 partial accumulators; chunk-of-4 gather combined at fin().
struct Acc4 {
    float q[4][4];
    __device__ __forceinline__ void init(const float4 b) {
        q[0][0]=b.x; q[0][1]=b.y; q[0][2]=b.z; q[0][3]=b.w;
        #pragma unroll
        for (int j = 1; j < 4; j++)
            #pragma unroll
            for (int i = 0; i < 4; i++) q[j][i] = 0.f;
    }
    __device__ __forceinline__ void fin(float out[4]) {
        #pragma unroll
        for (int i = 0; i < 4; i++) out[i] = (q[0][i]+q[1][i]) + (q[2][i]+q[3][i]);
    }
};

// gather columns col = base + bit*CMUL of Wt ([*][256] f-major) for set bits of
// uniform mask m. 4 independent loads per chunk -> 1 waitcnt -> 16 fma.
// Remainder lanes re-load col c0 with multiplier 0 (exact no-op).
template<int CMUL>
__device__ __forceinline__ void gather4(Acc4& A, const float* __restrict__ Wt,
                                        u64 m, u32 base, u32 lane4) {
    const float* __restrict__ Wb = Wt + ((size_t)base << 8) + lane4;
    while (m) {
        u32 c0 = (u32)__builtin_ctzll(m); m &= m - 1;
        bool h1 = m != 0; u32 c1 = h1 ? (u32)__builtin_ctzll(m) : c0; m &= m - 1;
        bool h2 = m != 0; u32 c2 = h2 ? (u32)__builtin_ctzll(m) : c0; m &= m - 1;
        bool h3 = m != 0; u32 c3 = h3 ? (u32)__builtin_ctzll(m) : c0; m &= m - 1;
        const float4 w0 = *(const float4*)(Wb + ((size_t)c0 * CMUL << 8));
        const float4 w1 = *(const float4*)(Wb + ((size_t)c1 * CMUL << 8));
        const float4 w2 = *(const float4*)(Wb + ((size_t)c2 * CMUL << 8));
        const float4 w3 = *(const float4*)(Wb + ((size_t)c3 * CMUL << 8));
        const float f1 = h1 ? 1.f : 0.f;
        const float f2 = h2 ? 1.f : 0.f;
        const float f3 = h3 ? 1.f : 0.f;
        A.q[0][0] += w0.x; A.q[0][1] += w0.y; A.q[0][2] += w0.z; A.q[0][3] += w0.w;
        A.q[1][0] = fmaf(f1, w1.x, A.q[1][0]); A.q[1][1] = fmaf(f1, w1.y, A.q[1][1]);
        A.q[1][2] = fmaf(f1, w1.z, A.q[1][2]); A.q[1][3] = fmaf(f1, w1.w, A.q[1][3]);
        A.q[2][0] = fmaf(f2, w2.x, A.q[2][0]); A.q[2][1] = fmaf(f2, w2.y, A.q[2][1]);
        A.q[2][2] = fmaf(f2, w2.z, A.q[2][2]); A.q[2][3] = fmaf(f2, w2.w, A.q[2][3]);
        A.q[3][0] = fmaf(f3, w3.x, A.q[3][0]); A.q[3][1] = fmaf(f3, w3.y, A.q[3][1]);
        A.q[3][2] = fmaf(f3, w3.z, A.q[3][2]); A.q[3][3] = fmaf(f3, w3.w, A.q[3][3]);
    }
}

// One wave per batch row; lane owns hidden neurons 4*lane..4*lane+3 and encoder
// features f = k*64+lane. Spike sets = uniform ballot masks; no LDS, no barriers.
__global__ __launch_bounds__(256, 4) void snn_k(const void* __restrict__ xin,
                                                const float* __restrict__ ws,
                                                void* __restrict__ out) {
    const u32 isbf = ((const u32*)(ws + OFF_FLAG))[0];
    const u32 tid  = threadIdx.x;
    const u32 lane = tid & 63;
    const u32 wv   = tid >> 6;
    const int row  = blockIdx.x * 4 + wv;
    const u32 lane4 = lane * 4;

    const float* __restrict__ W1T = ws + OFF_W1T;
    const float* __restrict__ W2T = ws + OFF_W2T;
    const float* __restrict__ W3T = ws + OFF_W3T;
    const float* __restrict__ WLI = ws + OFF_WLI;

    float xf[16];
    if (isbf) {
        const __hip_bfloat16* xp = (const __hip_bfloat16*)xin + (size_t)row*FEAT;
        #pragma unroll
        for (int k = 0; k < 16; k++) xf[k] = __bfloat162float(xp[k*64 + lane]);
    } else {
        const float* xp = (const float*)xin + (size_t)row*FEAT;
        #pragma unroll
        for (int k = 0; k < 16; k++) xf[k] = xp[k*64 + lane];
    }

    float venc[16];
    #pragma unroll
    for (int k = 0; k < 16; k++) venc[k] = 0.0f;

    float v1[4], i1[4], v2[4], i2[4], v3[4], i3[4], g[4];
    #pragma unroll
    for (int k = 0; k < 4; k++) {
        v1[k]=0.f; i1[k]=0.f; v2[k]=0.f; i2[k]=0.f; v3[k]=0.f; i3[k]=0.f; g[k]=0.f;
    }
    const float4 b1v = *(const float4*)(ws + OFF_B1 + lane4);
    const float4 b2v = *(const float4*)(ws + OFF_B2 + lane4);
    const float4 b3v = *(const float4*)(ws + OFF_B3 + lane4);

    for (int t = 0; t < TSTEPS; t++) {
        // ---- encoder + fused layer-1 gather ----
        Acc4 A1; A1.init(b1v);
        #pragma unroll
        for (int k = 0; k < 16; k++) {
            float vd = venc[k] + 0.1f * (xf[k] - venc[k]);
            bool z = vd > 1.0f;
            venc[k] = z ? 0.0f : vd;
            u64 m = __ballot(z);
            gather4<1>(A1, W1T, m, (u32)(k << 6), lane4);
        }
        float a1[4]; A1.fin(a1);

        // ---- layer 1 LIF ----
        float o1v[4]; u64 m1[4];
        #pragma unroll
        for (int kk = 0; kk < 4; kk++) {
            float vd = v1[kk] + 0.1f * (i1[kk] - v1[kk]);
            i1[kk] = i1[kk] * 0.8f;
            bool z = vd > 0.23f;
            v1[kk] = z ? 0.0f : vd;
            i1[kk] = i1[kk] + a1[kk];
            o1v[kk] = z ? 1.0f : 0.0f;
            m1[kk] = __ballot(z);
        }

        // ---- layer 2 gather (neuron index = 4*bit + kk) ----
        Acc4 A2; A2.init(b2v);
        #pragma unroll
        for (int kk = 0; kk < 4; kk++) gather4<4>(A2, W2T, m1[kk], (u32)kk, lane4);
        float a2[4]; A2.fin(a2);

        // ---- layer 2 LIF, o2 = z2 + o1 ----
        float o2v[4]; u64 m2[4];
        #pragma unroll
        for (int kk = 0; kk < 4; kk++) {
            float vd = v2[kk] + 0.1f * (i2[kk] - v2[kk]);
            i2[kk] = i2[kk] * 0.8f;
            bool z = vd > 0.23f;
            v2[kk] = z ? 0.0f : vd;
            i2[kk] = i2[kk] + a2[kk];
            o2v[kk] = (z ? 1.0f : 0.0f) + o1v[kk];
            m2[kk] = __ballot(z);
        }

        // ---- layer 3 gather: o2@W3 = z2@W3 + z1@W3 ----
        Acc4 A3; A3.init(b3v);
        #pragma unroll
        for (int kk = 0; kk < 4; kk++) gather4<4>(A3, W3T, m2[kk], (u32)kk, lane4);
        #pragma unroll
        for (int kk = 0; kk < 4; kk++) gather4<4>(A3, W3T, m1[kk], (u32)kk, lane4);
        float a3[4]; A3.fin(a3);

        // ---- layer 3 LIF, o3 = z3 + o2; linearized readout accumulation ----
        const float cf = COEF.c[t];
        #pragma unroll
        for (int kk = 0; kk < 4; kk++) {
            float vd = v3[kk] + 0.1f * (i3[kk] - v3[kk]);
            i3[kk] = i3[kk] * 0.8f;
            bool z = vd > 0.23f;
            v3[kk] = z ? 0.0f : vd;
            i3[kk] = i3[kk] + a3[kk];
            float o3 = (z ? 1.0f : 0.0f) + o2v[kk];
            g[kk] += cf * o3;
        }
    }

    // ---- epilogue: vo_24[c] = sum_h g[h]*Wli[c][h] ----
    float s[NCLS];
    #pragma unroll
    for (int c = 0; c < NCLS; c++) {
        const float4 w = *(const float4*)(WLI + c*HID + lane4);
        float p = g[0]*w.x + g[1]*w.y + g[2]*w.z + g[3]*w.w;
        #pragma unroll
        for (int d = 32; d > 0; d >>= 1) p += __shfl_xor(p, d, 64);
        s[c] = p;
    }
    if (lane == 0) {
        if (isbf) {
            __hip_bfloat16* o = (__hip_bfloat16*)out + (size_t)row*NCLS;
            #pragma unroll
            for (int c = 0; c < NCLS; c++) o[c] = __float2bfloat16(s[c]);
        } else {
            float* o = (float*)out + (size_t)row*NCLS;
            #pragma unroll
            for (int c = 0; c < NCLS; c++) o[c] = s[c];
        }
    }
}

extern "C" void kernel_launch(void* const* d_in, const int* in_sizes, int n_in,
                              void* d_out, int out_size, void* d_ws, size_t ws_size,
                              hipStream_t stream) {
    const void* x   = d_in[0];
    const void* W1  = d_in[1];
    const void* b1  = d_in[2];
    const void* W2  = d_in[3];
    const void* b2  = d_in[4];
    const void* W3  = d_in[5];
    const void* b3  = d_in[6];
    const void* Wli = d_in[7];
    float* ws = (float*)d_ws;
    const int batch = in_sizes[0] / FEAT;   // 4096

    u32* flag = (u32*)(ws + OFF_FLAG);
    detect_dtype_k<<<1, 256, 0, stream>>>(x, flag);

    const int prep_elems = FEAT*HID + HID*HID + HID*HID + NCLS*HID + 3*HID;
    prep_weights_k<<<(prep_elems + 255)/256, 256, 0, stream>>>(W1, W2, W3, Wli, b1, b2, b3, ws);

    snn_k<<<batch/4, 256, 0, stream>>>(x, ws, d_out);
}

// Round 4
// 266.960 us; speedup vs baseline: 1.6466x; 1.6466x over previous
//
#include <hip/hip_runtime.h>
#include <hip/hip_bf16.h>

#define FEAT   1024
#define HID    256
#define TSTEPS 24
#define NCLS   10

typedef unsigned int u32;
typedef unsigned long long u64;

// ---- workspace layout (float offsets) ----
constexpr int OFF_W1T  = 0;                    // [1024][256] fp32, f-major (W1 transposed)
constexpr int OFF_W2T  = OFF_W1T + FEAT*HID;   // [256][256]  fp32, f-major
constexpr int OFF_W3T  = OFF_W2T + HID*HID;    // [256][256]  fp32, f-major
constexpr int OFF_WLI  = OFF_W3T + HID*HID;    // [10][256]   fp32, plain copy
constexpr int OFF_B1   = OFF_WLI + NCLS*HID;
constexpr int OFF_B2   = OFF_B1 + HID;
constexpr int OFF_B3   = OFF_B2 + HID;

// ---- LI readout linearized: vo_24 = sum_t coef[t] * (o3_t @ Wli^T).
// c_23 = 0; c_{u-1} = 0.8*c_u + 0.1*0.9^(23-u).
struct CoefT { float c[TSTEPS]; };
constexpr CoefT make_coef() {
    CoefT r{};
    double c = 0.0, p9 = 1.0;
    r.c[TSTEPS-1] = 0.0f;
    for (int u = TSTEPS-1; u > 0; u--) {
        c = 0.8 * c + 0.1 * p9;
        p9 *= 0.9;
        r.c[u-1] = (float)c;
    }
    return r;
}
__device__ constexpr CoefT COEF = make_coef();

// ---- in-wave dtype detect: fp32 data viewed as bf16 -> mantissa-as-exponent
// garbage (huge/NaN) at even indices; true bf16 N(0,1) stays small. Uniform
// across the wave via ballot; no atomics, no extra kernel.
__device__ __forceinline__ u32 detect_bf16(const void* __restrict__ x, u32 lane) {
    float v = __bfloat162float(((const __hip_bfloat16*)x)[lane]);
    u64 bad = __ballot(!(fabsf(v) < 100.0f));
    return bad == 0ull ? 1u : 0u;
}

__device__ __forceinline__ float rd_any(const void* p, int idx, u32 isbf) {
    return isbf ? __bfloat162float(((const __hip_bfloat16*)p)[idx])
                : ((const float*)p)[idx];
}

// ---- prep: COALESCED reads, scattered writes (stores don't stall) ----
__global__ void prep_weights_k(const void* __restrict__ x,
                               const void* W1, const void* W2, const void* W3,
                               const void* Wli, const void* b1, const void* b2,
                               const void* b3, float* __restrict__ ws) {
    const u32 isbf = detect_bf16(x, threadIdx.x & 63);
    int id = blockIdx.x * 256 + threadIdx.x;
    if (id < FEAT*HID) {                 // read W1[h][f] contiguous; write W1T[f][h]
        int h = id >> 10, f = id & 1023;
        ws[OFF_W1T + f*HID + h] = rd_any(W1, id, isbf);
        return;
    }
    id -= FEAT*HID;
    if (id < HID*HID) {
        int h = id >> 8, f = id & 255;
        ws[OFF_W2T + f*HID + h] = rd_any(W2, id, isbf);
        return;
    }
    id -= HID*HID;
    if (id < HID*HID) {
        int h = id >> 8, f = id & 255;
        ws[OFF_W3T + f*HID + h] = rd_any(W3, id, isbf);
        return;
    }
    id -= HID*HID;
    if (id < NCLS*HID) { ws[OFF_WLI + id] = rd_any(Wli, id, isbf); return; }
    id -= NCLS*HID;
    if (id < HID) { ws[OFF_B1 + id] = rd_any(b1, id, isbf); return; }
    id -= HID;
    if (id < HID) { ws[OFF_B2 + id] = rd_any(b2, id, isbf); return; }
    id -= HID;
    if (id < HID) { ws[OFF_B3 + id] = rd_any(b3, id, isbf); return; }
}

// 4 partial accumulators; chunk-of-4 gather combined at fin().
struct Acc4 {
    float q[4][4];
    __device__ __forceinline__ void init(const float4 b) {
        q[0][0]=b.x; q[0][1]=b.y; q[0][2]=b.z; q[0][3]=b.w;
        #pragma unroll
        for (int j = 1; j < 4; j++)
            #pragma unroll
            for (int i = 0; i < 4; i++) q[j][i] = 0.f;
    }
    __device__ __forceinline__ void fin(float out[4]) {
        #pragma unroll
        for (int i = 0; i < 4; i++) out[i] = (q[0][i]+q[1][i]) + (q[2][i]+q[3][i]);
    }
};

// gather columns col = base + bit*CMUL of Wt ([*][256] f-major) for set bits of
// uniform mask m. 4 independent loads per chunk -> one latency -> 16 fma.
// Remainder lanes re-load col c0 (L1 hit) with multiplier 0 (exact no-op).
template<int CMUL>
__device__ __forceinline__ void gather4(Acc4& A, const float* __restrict__ Wt,
                                        u64 m, u32 base, u32 lane4) {
    const float* __restrict__ Wb = Wt + ((size_t)base << 8) + lane4;
    while (m) {
        u32 c0 = (u32)__builtin_ctzll(m); m &= m - 1;
        bool h1 = m != 0; u32 c1 = h1 ? (u32)__builtin_ctzll(m) : c0; m &= m - 1;
        bool h2 = m != 0; u32 c2 = h2 ? (u32)__builtin_ctzll(m) : c0; m &= m - 1;
        bool h3 = m != 0; u32 c3 = h3 ? (u32)__builtin_ctzll(m) : c0; m &= m - 1;
        const float4 w0 = *(const float4*)(Wb + ((size_t)c0 * CMUL << 8));
        const float4 w1 = *(const float4*)(Wb + ((size_t)c1 * CMUL << 8));
        const float4 w2 = *(const float4*)(Wb + ((size_t)c2 * CMUL << 8));
        const float4 w3 = *(const float4*)(Wb + ((size_t)c3 * CMUL << 8));
        const float f1 = h1 ? 1.f : 0.f;
        const float f2 = h2 ? 1.f : 0.f;
        const float f3 = h3 ? 1.f : 0.f;
        A.q[0][0] += w0.x; A.q[0][1] += w0.y; A.q[0][2] += w0.z; A.q[0][3] += w0.w;
        A.q[1][0] = fmaf(f1, w1.x, A.q[1][0]); A.q[1][1] = fmaf(f1, w1.y, A.q[1][1]);
        A.q[1][2] = fmaf(f1, w1.z, A.q[1][2]); A.q[1][3] = fmaf(f1, w1.w, A.q[1][3]);
        A.q[2][0] = fmaf(f2, w2.x, A.q[2][0]); A.q[2][1] = fmaf(f2, w2.y, A.q[2][1]);
        A.q[2][2] = fmaf(f2, w2.z, A.q[2][2]); A.q[2][3] = fmaf(f2, w2.w, A.q[2][3]);
        A.q[3][0] = fmaf(f3, w3.x, A.q[3][0]); A.q[3][1] = fmaf(f3, w3.y, A.q[3][1]);
        A.q[3][2] = fmaf(f3, w3.z, A.q[3][2]); A.q[3][3] = fmaf(f3, w3.w, A.q[3][3]);
    }
}

// One wave per batch row; lane owns hidden neurons 4*lane..4*lane+3 and encoder
// features f = k*64+lane. Spike sets = uniform ballot masks; no LDS, no barriers.
// NOTE: plain __launch_bounds__(256) — a min-waves/EU clamp here caused a 64-VGPR
// cap and 1.2 GB/dispatch of scratch spill (R3). Register demand is ~120-160.
__global__ __launch_bounds__(256) void snn_k(const void* __restrict__ xin,
                                             const float* __restrict__ ws,
                                             void* __restrict__ out) {
    const u32 tid  = threadIdx.x;
    const u32 lane = tid & 63;
    const u32 wv   = tid >> 6;
    const int row  = blockIdx.x * 4 + wv;
    const u32 lane4 = lane * 4;
    const u32 isbf = detect_bf16(xin, lane);

    const float* __restrict__ W1T = ws + OFF_W1T;
    const float* __restrict__ W2T = ws + OFF_W2T;
    const float* __restrict__ W3T = ws + OFF_W3T;
    const float* __restrict__ WLI = ws + OFF_WLI;

    float xf[16];
    if (isbf) {
        const __hip_bfloat16* xp = (const __hip_bfloat16*)xin + (size_t)row*FEAT;
        #pragma unroll
        for (int k = 0; k < 16; k++) xf[k] = __bfloat162float(xp[k*64 + lane]);
    } else {
        const float* xp = (const float*)xin + (size_t)row*FEAT;
        #pragma unroll
        for (int k = 0; k < 16; k++) xf[k] = xp[k*64 + lane];
    }

    float venc[16];
    #pragma unroll
    for (int k = 0; k < 16; k++) venc[k] = 0.0f;

    float v1[4], i1[4], v2[4], i2[4], v3[4], i3[4], g[4];
    #pragma unroll
    for (int k = 0; k < 4; k++) {
        v1[k]=0.f; i1[k]=0.f; v2[k]=0.f; i2[k]=0.f; v3[k]=0.f; i3[k]=0.f; g[k]=0.f;
    }
    const float4 b1v = *(const float4*)(ws + OFF_B1 + lane4);
    const float4 b2v = *(const float4*)(ws + OFF_B2 + lane4);
    const float4 b3v = *(const float4*)(ws + OFF_B3 + lane4);

    for (int t = 0; t < TSTEPS; t++) {
        // ---- encoder + fused layer-1 gather ----
        Acc4 A1; A1.init(b1v);
        #pragma unroll
        for (int k = 0; k < 16; k++) {
            float vd = venc[k] + 0.1f * (xf[k] - venc[k]);
            bool z = vd > 1.0f;
            venc[k] = z ? 0.0f : vd;
            u64 m = __ballot(z);
            gather4<1>(A1, W1T, m, (u32)(k << 6), lane4);
        }
        float a1[4]; A1.fin(a1);

        // ---- layer 1 LIF ----
        float o1v[4]; u64 m1[4];
        #pragma unroll
        for (int kk = 0; kk < 4; kk++) {
            float vd = v1[kk] + 0.1f * (i1[kk] - v1[kk]);
            i1[kk] = i1[kk] * 0.8f;
            bool z = vd > 0.23f;
            v1[kk] = z ? 0.0f : vd;
            i1[kk] = i1[kk] + a1[kk];
            o1v[kk] = z ? 1.0f : 0.0f;
            m1[kk] = __ballot(z);
        }

        // ---- layer 2 gather (neuron index = 4*bit + kk) ----
        Acc4 A2; A2.init(b2v);
        #pragma unroll
        for (int kk = 0; kk < 4; kk++) gather4<4>(A2, W2T, m1[kk], (u32)kk, lane4);
        float a2[4]; A2.fin(a2);

        // ---- layer 2 LIF, o2 = z2 + o1 ----
        float o2v[4]; u64 m2[4];
        #pragma unroll
        for (int kk = 0; kk < 4; kk++) {
            float vd = v2[kk] + 0.1f * (i2[kk] - v2[kk]);
            i2[kk] = i2[kk] * 0.8f;
            bool z = vd > 0.23f;
            v2[kk] = z ? 0.0f : vd;
            i2[kk] = i2[kk] + a2[kk];
            o2v[kk] = (z ? 1.0f : 0.0f) + o1v[kk];
            m2[kk] = __ballot(z);
        }

        // ---- layer 3 gather: o2@W3 = z2@W3 + z1@W3 (binary masks, exact) ----
        Acc4 A3; A3.init(b3v);
        #pragma unroll
        for (int kk = 0; kk < 4; kk++) gather4<4>(A3, W3T, m2[kk], (u32)kk, lane4);
        #pragma unroll
        for (int kk = 0; kk < 4; kk++) gather4<4>(A3, W3T, m1[kk], (u32)kk, lane4);
        float a3[4]; A3.fin(a3);

        // ---- layer 3 LIF, o3 = z3 + o2; linearized readout accumulation ----
        const float cf = COEF.c[t];
        #pragma unroll
        for (int kk = 0; kk < 4; kk++) {
            float vd = v3[kk] + 0.1f * (i3[kk] - v3[kk]);
            i3[kk] = i3[kk] * 0.8f;
            bool z = vd > 0.23f;
            v3[kk] = z ? 0.0f : vd;
            i3[kk] = i3[kk] + a3[kk];
            float o3 = (z ? 1.0f : 0.0f) + o2v[kk];
            g[kk] += cf * o3;
        }
    }

    // ---- epilogue: vo_24[c] = sum_h g[h]*Wli[c][h] ----
    float s[NCLS];
    #pragma unroll
    for (int c = 0; c < NCLS; c++) {
        const float4 w = *(const float4*)(WLI + c*HID + lane4);
        float p = g[0]*w.x + g[1]*w.y + g[2]*w.z + g[3]*w.w;
        #pragma unroll
        for (int d = 32; d > 0; d >>= 1) p += __shfl_xor(p, d, 64);
        s[c] = p;
    }
    if (lane == 0) {
        if (isbf) {
            __hip_bfloat16* o = (__hip_bfloat16*)out + (size_t)row*NCLS;
            #pragma unroll
            for (int c = 0; c < NCLS; c++) o[c] = __float2bfloat16(s[c]);
        } else {
            float* o = (float*)out + (size_t)row*NCLS;
            #pragma unroll
            for (int c = 0; c < NCLS; c++) o[c] = s[c];
        }
    }
}

extern "C" void kernel_launch(void* const* d_in, const int* in_sizes, int n_in,
                              void* d_out, int out_size, void* d_ws, size_t ws_size,
                              hipStream_t stream) {
    const void* x   = d_in[0];
    const void* W1  = d_in[1];
    const void* b1  = d_in[2];
    const void* W2  = d_in[3];
    const void* b2  = d_in[4];
    const void* W3  = d_in[5];
    const void* b3  = d_in[6];
    const void* Wli = d_in[7];
    float* ws = (float*)d_ws;
    const int batch = in_sizes[0] / FEAT;   // 4096

    const int prep_elems = FEAT*HID + HID*HID + HID*HID + NCLS*HID + 3*HID;
    prep_weights_k<<<(prep_elems + 255)/256, 256, 0, stream>>>(x, W1, W2, W3, Wli, b1, b2, b3, ws);

    snn_k<<<batch/4, 256, 0, stream>>>(x, ws, d_out);
}

// Round 5
// 177.810 us; speedup vs baseline: 2.4722x; 1.5014x over previous
//
#include <hip/hip_runtime.h>
#include <hip/hip_bf16.h>

#define FEAT   1024
#define HID    256
#define TSTEPS 24
#define NCLS   10

typedef unsigned int u32;
typedef unsigned long long u64;
typedef unsigned short u16;

// ---- workspace layout (float offsets) ----
constexpr int OFF_W1T  = 0;                    // [1024][256] fp32 (W1^T)
constexpr int OFF_W2T  = OFF_W1T + FEAT*HID;   // [256][256]  fp32
constexpr int OFF_W3T  = OFF_W2T + HID*HID;    // [256][256]  fp32
constexpr int OFF_WLI  = OFF_W3T + HID*HID;    // [10][256]   fp32 plain copy
constexpr int OFF_B1   = OFF_WLI + NCLS*HID;
constexpr int OFF_B2   = OFF_B1 + HID;
constexpr int OFF_B3   = OFF_B2 + HID;

// ---- LI readout linearized: vo_24 = sum_t coef[t] * (o3_t @ Wli^T).
struct CoefT { float c[TSTEPS]; };
constexpr CoefT make_coef() {
    CoefT r{};
    double c = 0.0, p9 = 1.0;
    r.c[TSTEPS-1] = 0.0f;
    for (int u = TSTEPS-1; u > 0; u--) {
        c = 0.8 * c + 0.1 * p9;
        p9 *= 0.9;
        r.c[u-1] = (float)c;
    }
    return r;
}
__device__ constexpr CoefT COEF = make_coef();

// ---- in-wave dtype detect: fp32 viewed as bf16 -> exponent garbage at even idx.
__device__ __forceinline__ u32 detect_bf16(const void* __restrict__ x, u32 lane) {
    float v = __bfloat162float(((const __hip_bfloat16*)x)[lane]);
    u64 bad = __ballot(!(fabsf(v) < 100.0f));
    return bad == 0ull ? 1u : 0u;
}

__device__ __forceinline__ float rd_any(const void* p, int idx, u32 isbf) {
    return isbf ? __bfloat162float(((const __hip_bfloat16*)p)[idx])
                : ((const float*)p)[idx];
}

// ---- prep: LDS-tiled 64x64 transpose, coalesced reads AND writes ----
// blocks 0..63: W1 [256][1024]->W1T ; 64..79: W2 ; 80..95: W3 ; 96: Wli+biases
__global__ __launch_bounds__(256) void prep_weights_k(const void* __restrict__ x,
        const void* W1, const void* W2, const void* W3, const void* Wli,
        const void* b1, const void* b2, const void* b3, float* __restrict__ ws) {
    const u32 isbf = detect_bf16(x, threadIdx.x & 63);
    const int b = blockIdx.x;
    const u32 tid = threadIdx.x;

    if (b == 96) {   // Wli copy + biases (coalesced)
        for (u32 e = tid; e < NCLS*HID; e += 256) ws[OFF_WLI + e] = rd_any(Wli, e, isbf);
        for (u32 e = tid; e < 3*HID; e += 256) {
            u32 which = e >> 8, idx = e & 255;
            const void* src = which == 0 ? b1 : (which == 1 ? b2 : b3);
            int off = which == 0 ? OFF_B1 : (which == 1 ? OFF_B2 : OFF_B3);
            ws[off + idx] = rd_any(src, idx, isbf);
        }
        return;
    }

    const void* src; float* dst; int srcW, h0, f0;
    if (b < 64)      { src = W1; dst = ws + OFF_W1T; srcW = FEAT; h0 = (b >> 4) * 64; f0 = (b & 15) * 64; }
    else if (b < 80) { int tb = b - 64; src = W2; dst = ws + OFF_W2T; srcW = HID; h0 = (tb >> 2) * 64; f0 = (tb & 3) * 64; }
    else             { int tb = b - 80; src = W3; dst = ws + OFF_W3T; srcW = HID; h0 = (tb >> 2) * 64; f0 = (tb & 3) * 64; }

    __shared__ float sm[64][65];
    const u32 c = tid & 63, r0 = tid >> 6;
    #pragma unroll
    for (int i = 0; i < 16; i++) {
        u32 r = r0 + 4 * i;
        sm[r][c] = rd_any(src, (h0 + r) * srcW + f0 + c, isbf);
    }
    __syncthreads();
    #pragma unroll
    for (int i = 0; i < 16; i++) {
        u32 r = r0 + 4 * i;                       // row in dst (f), col c (h)
        dst[(size_t)(f0 + r) * HID + h0 + c] = sm[c][r];
    }
}

// ---- layer gather: two-level mask stream, chunk-of-4 loads in flight ----
// lm: per-lane local mask (<= MJ+1 bits meaningful... up to 16 bits). Column
// for word p (lane) bit j: col = (p<<SH) + (j&MJ). All control state uniform
// (SGPRs): act from ballot, cur via readlane, ctz chains on scalar pipe.
template<int SH, int MJ>
__device__ __forceinline__ void gather_stream(float acc[4], const float* __restrict__ Wt,
                                              u32 lm, u32 lane4) {
    u64 act = __ballot(lm != 0u);
    if (!act) return;
    u32 p = (u32)__builtin_ctzll(act); act &= act - 1;
    u32 cur = (u32)__builtin_amdgcn_readlane((int)lm, (int)p);
    for (;;) {
        u32 j = (u32)__builtin_ctz(cur); cur &= cur - 1;
        const u32 c0 = (p << SH) + (j & (u32)MJ);
        u32 c1 = c0, c2 = c0, c3 = c0;
        float f1 = 0.f, f2 = 0.f, f3 = 0.f;
        if (cur || act) {
            if (!cur) { p = (u32)__builtin_ctzll(act); act &= act - 1;
                        cur = (u32)__builtin_amdgcn_readlane((int)lm, (int)p); }
            j = (u32)__builtin_ctz(cur); cur &= cur - 1;
            c1 = (p << SH) + (j & (u32)MJ); f1 = 1.f;
        }
        if (cur || act) {
            if (!cur) { p = (u32)__builtin_ctzll(act); act &= act - 1;
                        cur = (u32)__builtin_amdgcn_readlane((int)lm, (int)p); }
            j = (u32)__builtin_ctz(cur); cur &= cur - 1;
            c2 = (p << SH) + (j & (u32)MJ); f2 = 1.f;
        }
        if (cur || act) {
            if (!cur) { p = (u32)__builtin_ctzll(act); act &= act - 1;
                        cur = (u32)__builtin_amdgcn_readlane((int)lm, (int)p); }
            j = (u32)__builtin_ctz(cur); cur &= cur - 1;
            c3 = (p << SH) + (j & (u32)MJ); f3 = 1.f;
        }
        // 4 independent loads (scalar base + lane offset), one wait, 16 fma
        const float4 w0 = *(const float4*)(Wt + ((size_t)c0 << 8) + lane4);
        const float4 w1 = *(const float4*)(Wt + ((size_t)c1 << 8) + lane4);
        const float4 w2 = *(const float4*)(Wt + ((size_t)c2 << 8) + lane4);
        const float4 w3 = *(const float4*)(Wt + ((size_t)c3 << 8) + lane4);
        acc[0] += w0.x; acc[1] += w0.y; acc[2] += w0.z; acc[3] += w0.w;
        acc[0] = fmaf(f1, w1.x, acc[0]); acc[1] = fmaf(f1, w1.y, acc[1]);
        acc[2] = fmaf(f1, w1.z, acc[2]); acc[3] = fmaf(f1, w1.w, acc[3]);
        acc[0] = fmaf(f2, w2.x, acc[0]); acc[1] = fmaf(f2, w2.y, acc[1]);
        acc[2] = fmaf(f2, w2.z, acc[2]); acc[3] = fmaf(f2, w2.w, acc[3]);
        acc[0] = fmaf(f3, w3.x, acc[0]); acc[1] = fmaf(f3, w3.y, acc[1]);
        acc[2] = fmaf(f3, w3.z, acc[2]); acc[3] = fmaf(f3, w3.w, acc[3]);
        if (!cur && !act) return;
        if (!cur) { p = (u32)__builtin_ctzll(act); act &= act - 1;
                    cur = (u32)__builtin_amdgcn_readlane((int)lm, (int)p); }
    }
}

// One wave per batch row. Lane owns encoder features [16L..16L+16) and hidden
// neurons 4L..4L+3. Encoder spike schedules (deterministic from x) precomputed
// into LDS (2 steps per u32). t-loop NOT unrolled (I-cache — R4 lesson).
__global__ __launch_bounds__(256) void snn_k(const void* __restrict__ xin,
                                             const float* __restrict__ ws,
                                             void* __restrict__ out) {
    const u32 tid  = threadIdx.x;
    const u32 lane = tid & 63;
    const u32 wv   = tid >> 6;
    const int row  = blockIdx.x * 4 + wv;
    const u32 lane4 = lane * 4;
    const u32 isbf = detect_bf16(xin, lane);

    const float* __restrict__ W1T = ws + OFF_W1T;
    const float* __restrict__ W2T = ws + OFF_W2T;
    const float* __restrict__ W3T = ws + OFF_W3T;
    const float* __restrict__ WLI = ws + OFF_WLI;

    __shared__ u32 sched[12 * 256];   // [pair][tid], conflict-free both phases

    // ---- encoder precompute: 24-step spike schedule for my 16 features ----
    {
        float xv[16];
        if (isbf) {
            const uint4* xp = (const uint4*)((const u16*)xin + (size_t)row*FEAT + lane*16);
            uint4 A = xp[0], B = xp[1];
            u32 w[8] = {A.x, A.y, A.z, A.w, B.x, B.y, B.z, B.w};
            #pragma unroll
            for (int i = 0; i < 8; i++) {
                xv[2*i]   = __uint_as_float(w[i] << 16);
                xv[2*i+1] = __uint_as_float(w[i] & 0xffff0000u);
            }
        } else {
            const float4* xp = (const float4*)((const float*)xin + (size_t)row*FEAT + lane*16);
            float4 A = xp[0], B = xp[1], C = xp[2], D = xp[3];
            float tmp[16] = {A.x,A.y,A.z,A.w,B.x,B.y,B.z,B.w,C.x,C.y,C.z,C.w,D.x,D.y,D.z,D.w};
            #pragma unroll
            for (int i = 0; i < 16; i++) xv[i] = tmp[i];
        }
        u32 smreg[12];
        #pragma unroll
        for (int i = 0; i < 12; i++) smreg[i] = 0;
        #pragma unroll
        for (int j = 0; j < 16; j++) {
            float v = 0.f;
            #pragma unroll
            for (int t = 0; t < TSTEPS; t++) {
                v = v + 0.1f * (xv[j] - v);
                bool z = v > 1.0f;
                v = z ? 0.0f : v;
                if (z) smreg[t >> 1] |= 1u << (((t & 1) << 4) + j);
            }
        }
        #pragma unroll
        for (int i = 0; i < 12; i++) sched[i * 256 + tid] = smreg[i];
        // each lane reads back only its own words -> no barrier needed
    }

    float v1[4], i1[4], v2[4], i2[4], v3[4], i3[4], g[4];
    #pragma unroll
    for (int k = 0; k < 4; k++) {
        v1[k]=0.f; i1[k]=0.f; v2[k]=0.f; i2[k]=0.f; v3[k]=0.f; i3[k]=0.f; g[k]=0.f;
    }
    const float4 b1v = *(const float4*)(ws + OFF_B1 + lane4);
    const float4 b2v = *(const float4*)(ws + OFF_B2 + lane4);
    const float4 b3v = *(const float4*)(ws + OFF_B3 + lane4);

    u32 pairreg = 0;
    for (int t = 0; t < TSTEPS; t++) {
        if ((t & 1) == 0) pairreg = sched[(t >> 1) * 256 + tid];
        const u32 lmE = (t & 1) ? (pairreg >> 16) : (pairreg & 0xffffu);

        // ---- layer 1: gather W1T cols for encoder spikes (col = 16p + j) ----
        float a1[4] = {b1v.x, b1v.y, b1v.z, b1v.w};
        gather_stream<4, 15>(a1, W1T, lmE, lane4);

        float o1v[4]; u32 lm1 = 0;
        #pragma unroll
        for (int kk = 0; kk < 4; kk++) {
            float vd = v1[kk] + 0.1f * (i1[kk] - v1[kk]);
            i1[kk] = i1[kk] * 0.8f;
            bool z = vd > 0.23f;
            v1[kk] = z ? 0.0f : vd;
            i1[kk] = i1[kk] + a1[kk];
            o1v[kk] = z ? 1.0f : 0.0f;
            lm1 |= (z ? 1u : 0u) << kk;
        }

        // ---- layer 2 (col = 4p + j) ----
        float a2[4] = {b2v.x, b2v.y, b2v.z, b2v.w};
        gather_stream<2, 3>(a2, W2T, lm1, lane4);

        float o2v[4]; u32 lm2 = 0;
        #pragma unroll
        for (int kk = 0; kk < 4; kk++) {
            float vd = v2[kk] + 0.1f * (i2[kk] - v2[kk]);
            i2[kk] = i2[kk] * 0.8f;
            bool z = vd > 0.23f;
            v2[kk] = z ? 0.0f : vd;
            i2[kk] = i2[kk] + a2[kk];
            o2v[kk] = (z ? 1.0f : 0.0f) + o1v[kk];
            lm2 |= (z ? 1u : 0u) << kk;
        }

        // ---- layer 3: o2@W3 = z2@W3 + z1@W3; combined 8-bit local mask,
        //      col = 4p + (j&3) (j>=4 bits repeat the col -> exact adds) ----
        float a3[4] = {b3v.x, b3v.y, b3v.z, b3v.w};
        gather_stream<2, 3>(a3, W3T, lm2 | (lm1 << 4), lane4);

        const float cf = COEF.c[t];
        #pragma unroll
        for (int kk = 0; kk < 4; kk++) {
            float vd = v3[kk] + 0.1f * (i3[kk] - v3[kk]);
            i3[kk] = i3[kk] * 0.8f;
            bool z = vd > 0.23f;
            v3[kk] = z ? 0.0f : vd;
            i3[kk] = i3[kk] + a3[kk];
            float o3 = (z ? 1.0f : 0.0f) + o2v[kk];
            g[kk] += cf * o3;
        }
    }

    // ---- epilogue: vo_24[c] = sum_h g[h]*Wli[c][h] ----
    float s[NCLS];
    #pragma unroll
    for (int c = 0; c < NCLS; c++) {
        const float4 w = *(const float4*)(WLI + c*HID + lane4);
        float p = g[0]*w.x + g[1]*w.y + g[2]*w.z + g[3]*w.w;
        #pragma unroll
        for (int d = 32; d > 0; d >>= 1) p += __shfl_xor(p, d, 64);
        s[c] = p;
    }
    if (lane == 0) {
        if (isbf) {
            __hip_bfloat16* o = (__hip_bfloat16*)out + (size_t)row*NCLS;
            #pragma unroll
            for (int c = 0; c < NCLS; c++) o[c] = __float2bfloat16(s[c]);
        } else {
            float* o = (float*)out + (size_t)row*NCLS;
            #pragma unroll
            for (int c = 0; c < NCLS; c++) o[c] = s[c];
        }
    }
}

extern "C" void kernel_launch(void* const* d_in, const int* in_sizes, int n_in,
                              void* d_out, int out_size, void* d_ws, size_t ws_size,
                              hipStream_t stream) {
    const void* x   = d_in[0];
    const void* W1  = d_in[1];
    const void* b1  = d_in[2];
    const void* W2  = d_in[3];
    const void* b2  = d_in[4];
    const void* W3  = d_in[5];
    const void* b3  = d_in[6];
    const void* Wli = d_in[7];
    float* ws = (float*)d_ws;
    const int batch = in_sizes[0] / FEAT;   // 4096

    prep_weights_k<<<97, 256, 0, stream>>>(x, W1, W2, W3, Wli, b1, b2, b3, ws);
    snn_k<<<batch/4, 256, 0, stream>>>(x, ws, d_out);
}

// Round 6
// 156.820 us; speedup vs baseline: 2.8031x; 1.1338x over previous
//
#include <hip/hip_runtime.h>
#include <hip/hip_bf16.h>

#define FEAT   1024
#define HID    256
#define TSTEPS 24
#define NCLS   10

typedef unsigned int u32;
typedef unsigned long long u64;
typedef unsigned short u16;
typedef float v2f __attribute__((ext_vector_type(2)));

// ---- workspace layout (float offsets) ----
constexpr int OFF_W1T  = 0;                    // [1024][256] fp32 (W1^T)
constexpr int OFF_W2T  = OFF_W1T + FEAT*HID;   // [256][256]  fp32
constexpr int OFF_W3T  = OFF_W2T + HID*HID;    // [256][256]  fp32
constexpr int OFF_WLI  = OFF_W3T + HID*HID;    // [10][256]   fp32 plain copy
constexpr int OFF_B1   = OFF_WLI + NCLS*HID;
constexpr int OFF_B2   = OFF_B1 + HID;
constexpr int OFF_B3   = OFF_B2 + HID;

// ---- LI readout linearized: vo_24 = sum_t coef[t] * (o3_t @ Wli^T).
struct CoefT { float c[TSTEPS]; };
constexpr CoefT make_coef() {
    CoefT r{};
    double c = 0.0, p9 = 1.0;
    r.c[TSTEPS-1] = 0.0f;
    for (int u = TSTEPS-1; u > 0; u--) {
        c = 0.8 * c + 0.1 * p9;
        p9 *= 0.9;
        r.c[u-1] = (float)c;
    }
    return r;
}
__device__ constexpr CoefT COEF = make_coef();

// ---- in-wave dtype detect: fp32 viewed as bf16 -> exponent garbage at even idx.
__device__ __forceinline__ u32 detect_bf16(const void* __restrict__ x, u32 lane) {
    float v = __bfloat162float(((const __hip_bfloat16*)x)[lane]);
    u64 bad = __ballot(!(fabsf(v) < 100.0f));
    return bad == 0ull ? 1u : 0u;
}

__device__ __forceinline__ float rd_any(const void* p, int idx, u32 isbf) {
    return isbf ? __bfloat162float(((const __hip_bfloat16*)p)[idx])
                : ((const float*)p)[idx];
}

// float4 of elements [i, i+3] (i 4-aligned) from fp32 or bf16 source
__device__ __forceinline__ float4 rd4(const void* p, int i, u32 isbf) {
    if (isbf) {
        const u32* q = (const u32*)p;
        u32 a = q[i >> 1], b = q[(i >> 1) + 1];
        float4 r;
        r.x = __uint_as_float(a << 16); r.y = __uint_as_float(a & 0xffff0000u);
        r.z = __uint_as_float(b << 16); r.w = __uint_as_float(b & 0xffff0000u);
        return r;
    }
    return ((const float4*)p)[i >> 2];
}

// ---- prep: vectorized reads (16B fp32 / 8B bf16 per thread), scattered stores ----
// blocks 0..255: W1 ; 256..319: W2 ; 320..383: W3 ; 384: Wli + biases
__global__ __launch_bounds__(256) void prep_k(const void* __restrict__ x,
        const void* W1, const void* W2, const void* W3, const void* Wli,
        const void* b1, const void* b2, const void* b3, float* __restrict__ ws) {
    const u32 isbf = detect_bf16(x, threadIdx.x & 63);
    int b = blockIdx.x;
    const u32 t = threadIdx.x;
    if (b < 256) {
        int id = b * 256 + t;
        int h = id >> 8, f4 = (id & 255) << 2;
        float4 w = rd4(W1, h * FEAT + f4, isbf);
        float* d = ws + OFF_W1T;
        d[(f4+0)*HID + h] = w.x; d[(f4+1)*HID + h] = w.y;
        d[(f4+2)*HID + h] = w.z; d[(f4+3)*HID + h] = w.w;
        return;
    }
    b -= 256;
    if (b < 64) {
        int id = b * 256 + t;
        int h = id >> 6, f4 = (id & 63) << 2;
        float4 w = rd4(W2, h * HID + f4, isbf);
        float* d = ws + OFF_W2T;
        d[(f4+0)*HID + h] = w.x; d[(f4+1)*HID + h] = w.y;
        d[(f4+2)*HID + h] = w.z; d[(f4+3)*HID + h] = w.w;
        return;
    }
    b -= 64;
    if (b < 64) {
        int id = b * 256 + t;
        int h = id >> 6, f4 = (id & 63) << 2;
        float4 w = rd4(W3, h * HID + f4, isbf);
        float* d = ws + OFF_W3T;
        d[(f4+0)*HID + h] = w.x; d[(f4+1)*HID + h] = w.y;
        d[(f4+2)*HID + h] = w.z; d[(f4+3)*HID + h] = w.w;
        return;
    }
    // tail: Wli + biases
    for (u32 e = t; e < NCLS*HID; e += 256) ws[OFF_WLI + e] = rd_any(Wli, e, isbf);
    ws[OFF_B1 + t] = rd_any(b1, t, isbf);
    ws[OFF_B2 + t] = rd_any(b2, t, isbf);
    ws[OFF_B3 + t] = rd_any(b3, t, isbf);
}

__device__ __forceinline__ u32 mbcnt64(u64 m) {
    return __builtin_amdgcn_mbcnt_hi((u32)(m >> 32),
           __builtin_amdgcn_mbcnt_lo((u32)m, 0u));
}

// ---- list builders: branch-free prefix via weighted bit-plane ballots ----
// entries: (col | mult<<12) as u16; pad to multiple of 8 with mult=0 entries.

// masks over 4 neurons/lane (col = 4*lane + j); mult = bit(lmA)+bit(lmB)
__device__ __forceinline__ u32 build_list4(u16* list, u32 lmA, u32 lmB, u32 lane) {
    u32 u = lmA | lmB;
    u32 cnt = (u32)__builtin_popcount(u);
    u64 B0 = __ballot((cnt & 1u) != 0);
    u64 B1 = __ballot((cnt & 2u) != 0);
    u64 B2 = __ballot((cnt & 4u) != 0);
    u32 pos = mbcnt64(B0) + 2u*mbcnt64(B1) + 4u*mbcnt64(B2);
    u32 n = (u32)__builtin_popcountll(B0) + 2u*(u32)__builtin_popcountll(B1)
          + 4u*(u32)__builtin_popcountll(B2);
    while (u) {
        u32 j = (u32)__builtin_ctz(u); u &= u - 1;
        u32 mult = ((lmA >> j) & 1u) + ((lmB >> j) & 1u);
        list[pos++] = (u16)(((lane << 2) + j) | (mult << 12));
    }
    u32 pad = (8u - (n & 7u)) & 7u;
    if (lane < pad) list[n + lane] = 0;
    return n;
}

// encoder: 16 features/lane (col = 16*lane + j), mult = 1
__device__ __forceinline__ u32 build_listE(u16* list, u32 lm, u32 lane) {
    u32 cnt = (u32)__builtin_popcount(lm);
    u32 pos = 0, n = 0;
    #pragma unroll
    for (int b = 0; b < 5; b++) {
        u64 B = __ballot(((cnt >> b) & 1u) != 0);
        pos += mbcnt64(B) << b;
        n += ((u32)__builtin_popcountll(B)) << b;
    }
    while (lm) {
        u32 j = (u32)__builtin_ctz(lm); lm &= lm - 1;
        list[pos++] = (u16)(((lane << 4) + j) | 0x1000u);
    }
    u32 pad = (8u - (n & 7u)) & 7u;
    if (lane < pad) list[n + lane] = 0;
    return n;
}

// ---- uniform chunk gather: 8 cols/chunk, 1 ds_read_b128 + 8 dwordx4 loads +
// 16 packed fma. mult in bits 12+ (0 for pad -> exact no-op). ----
#define GSTEP(E, W) do { \
    float mm = (float)((E) >> 12); \
    v2f mv = {mm, mm}; \
    v2f lo = {(W).x, (W).y}, hi = {(W).z, (W).w}; \
    accA += mv * lo; accB += mv * hi; \
} while (0)

__device__ __forceinline__ void gather_list(v2f& accA, v2f& accB,
        const float* __restrict__ Wt, const u16* list, u32 n, u32 lane4) {
    u32 nch = (n + 7u) >> 3;
    const uint4* lp = (const uint4*)list;
    for (u32 c = 0; c < nch; c++) {
        uint4 d = lp[c];
        u32 e0 = d.x & 0xffffu, e1 = d.x >> 16;
        u32 e2 = d.y & 0xffffu, e3 = d.y >> 16;
        u32 e4 = d.z & 0xffffu, e5 = d.z >> 16;
        u32 e6 = d.w & 0xffffu, e7 = d.w >> 16;
        const float4 w0 = *(const float4*)(Wt + ((e0 & 0xfffu) << 8) + lane4);
        const float4 w1 = *(const float4*)(Wt + ((e1 & 0xfffu) << 8) + lane4);
        const float4 w2 = *(const float4*)(Wt + ((e2 & 0xfffu) << 8) + lane4);
        const float4 w3 = *(const float4*)(Wt + ((e3 & 0xfffu) << 8) + lane4);
        const float4 w4 = *(const float4*)(Wt + ((e4 & 0xfffu) << 8) + lane4);
        const float4 w5 = *(const float4*)(Wt + ((e5 & 0xfffu) << 8) + lane4);
        const float4 w6 = *(const float4*)(Wt + ((e6 & 0xfffu) << 8) + lane4);
        const float4 w7 = *(const float4*)(Wt + ((e7 & 0xfffu) << 8) + lane4);
        GSTEP(e0, w0); GSTEP(e1, w1); GSTEP(e2, w2); GSTEP(e3, w3);
        GSTEP(e4, w4); GSTEP(e5, w5); GSTEP(e6, w6); GSTEP(e7, w7);
    }
}

// One wave per batch row. Lane owns encoder features [16L..16L+16) and hidden
// neurons 4L..4L+3. Encoder spike schedule precomputed to LDS (2 steps/u32).
// t-loop rolled (I-cache). No barriers (all per-wave).
__global__ __launch_bounds__(256) void snn_k(const void* __restrict__ xin,
                                             const float* __restrict__ ws,
                                             void* __restrict__ out) {
    const u32 tid  = threadIdx.x;
    const u32 lane = tid & 63;
    const u32 wv   = tid >> 6;
    const int row  = blockIdx.x * 4 + wv;
    const u32 lane4 = lane * 4;
    const u32 isbf = detect_bf16(xin, lane);

    const float* __restrict__ W1T = ws + OFF_W1T;
    const float* __restrict__ W2T = ws + OFF_W2T;
    const float* __restrict__ W3T = ws + OFF_W3T;
    const float* __restrict__ WLI = ws + OFF_WLI;

    __shared__ u32 sched[12 * 256];            // 12 KB: encoder spike schedule
    __shared__ __align__(16) u16 listE[4][1040];  // 8.3 KB: per-wave L1 col list
    __shared__ __align__(16) u16 listL[4][272];   // 2.2 KB: per-wave L2/L3 list (reused)

    // ---- encoder precompute: 24-step spike schedule for my 16 features ----
    {
        float xv[16];
        if (isbf) {
            const uint4* xp = (const uint4*)((const u16*)xin + (size_t)row*FEAT + lane*16);
            uint4 A = xp[0], B = xp[1];
            u32 w[8] = {A.x, A.y, A.z, A.w, B.x, B.y, B.z, B.w};
            #pragma unroll
            for (int i = 0; i < 8; i++) {
                xv[2*i]   = __uint_as_float(w[i] << 16);
                xv[2*i+1] = __uint_as_float(w[i] & 0xffff0000u);
            }
        } else {
            const float4* xp = (const float4*)((const float*)xin + (size_t)row*FEAT + lane*16);
            float4 A = xp[0], B = xp[1], C = xp[2], D = xp[3];
            float tmp[16] = {A.x,A.y,A.z,A.w,B.x,B.y,B.z,B.w,C.x,C.y,C.z,C.w,D.x,D.y,D.z,D.w};
            #pragma unroll
            for (int i = 0; i < 16; i++) xv[i] = tmp[i];
        }
        u32 smreg[12];
        #pragma unroll
        for (int i = 0; i < 12; i++) smreg[i] = 0;
        #pragma unroll
        for (int j = 0; j < 16; j++) {
            float v = 0.f;
            #pragma unroll
            for (int t = 0; t < TSTEPS; t++) {
                v = v + 0.1f * (xv[j] - v);
                bool z = v > 1.0f;
                v = z ? 0.0f : v;
                if (z) smreg[t >> 1] |= 1u << (((t & 1) << 4) + j);
            }
        }
        #pragma unroll
        for (int i = 0; i < 12; i++) sched[i * 256 + tid] = smreg[i];
        // lanes read back only their own words -> no barrier needed
    }

    float v1[4], i1[4], v2[4], i2[4], v3[4], i3[4], g[4];
    #pragma unroll
    for (int k = 0; k < 4; k++) {
        v1[k]=0.f; i1[k]=0.f; v2[k]=0.f; i2[k]=0.f; v3[k]=0.f; i3[k]=0.f; g[k]=0.f;
    }
    const float4 b1v = *(const float4*)(ws + OFF_B1 + lane4);
    const float4 b2v = *(const float4*)(ws + OFF_B2 + lane4);
    const float4 b3v = *(const float4*)(ws + OFF_B3 + lane4);

    u16* const lE = listE[wv];
    u16* const lL = listL[wv];

    u32 pairreg = 0;
    for (int t = 0; t < TSTEPS; t++) {
        if ((t & 1) == 0) pairreg = sched[(t >> 1) * 256 + tid];
        const u32 lmE = (t & 1) ? (pairreg >> 16) : (pairreg & 0xffffu);

        // ---- layer 1 ----
        u32 nE = build_listE(lE, lmE, lane);
        v2f accA = {b1v.x, b1v.y}, accB = {b1v.z, b1v.w};
        gather_list(accA, accB, W1T, lE, nE, lane4);
        float a1[4] = {accA.x, accA.y, accB.x, accB.y};

        float o1v[4]; u32 lm1 = 0;
        #pragma unroll
        for (int kk = 0; kk < 4; kk++) {
            float vd = v1[kk] + 0.1f * (i1[kk] - v1[kk]);
            i1[kk] = i1[kk] * 0.8f;
            bool z = vd > 0.23f;
            v1[kk] = z ? 0.0f : vd;
            i1[kk] = i1[kk] + a1[kk];
            o1v[kk] = z ? 1.0f : 0.0f;
            lm1 |= (z ? 1u : 0u) << kk;
        }

        // ---- layer 2 (mult = 1) ----
        u32 n1 = build_list4(lL, lm1, 0u, lane);
        accA = (v2f){b2v.x, b2v.y}; accB = (v2f){b2v.z, b2v.w};
        gather_list(accA, accB, W2T, lL, n1, lane4);
        float a2[4] = {accA.x, accA.y, accB.x, accB.y};

        float o2v[4]; u32 lm2 = 0;
        #pragma unroll
        for (int kk = 0; kk < 4; kk++) {
            float vd = v2[kk] + 0.1f * (i2[kk] - v2[kk]);
            i2[kk] = i2[kk] * 0.8f;
            bool z = vd > 0.23f;
            v2[kk] = z ? 0.0f : vd;
            i2[kk] = i2[kk] + a2[kk];
            o2v[kk] = (z ? 1.0f : 0.0f) + o1v[kk];
            lm2 |= (z ? 1u : 0u) << kk;
        }

        // ---- layer 3: o2 = z1 + z2 -> union cols, mult in entry bits 12+ ----
        u32 n2 = build_list4(lL, lm1, lm2, lane);
        accA = (v2f){b3v.x, b3v.y}; accB = (v2f){b3v.z, b3v.w};
        gather_list(accA, accB, W3T, lL, n2, lane4);
        float a3[4] = {accA.x, accA.y, accB.x, accB.y};

        const float cf = COEF.c[t];
        #pragma unroll
        for (int kk = 0; kk < 4; kk++) {
            float vd = v3[kk] + 0.1f * (i3[kk] - v3[kk]);
            i3[kk] = i3[kk] * 0.8f;
            bool z = vd > 0.23f;
            v3[kk] = z ? 0.0f : vd;
            i3[kk] = i3[kk] + a3[kk];
            float o3 = (z ? 1.0f : 0.0f) + o2v[kk];
            g[kk] += cf * o3;
        }
    }

    // ---- epilogue: vo_24[c] = sum_h g[h]*Wli[c][h] ----
    float s[NCLS];
    #pragma unroll
    for (int c = 0; c < NCLS; c++) {
        const float4 w = *(const float4*)(WLI + c*HID + lane4);
        float p = g[0]*w.x + g[1]*w.y + g[2]*w.z + g[3]*w.w;
        #pragma unroll
        for (int d = 32; d > 0; d >>= 1) p += __shfl_xor(p, d, 64);
        s[c] = p;
    }
    if (lane == 0) {
        if (isbf) {
            __hip_bfloat16* o = (__hip_bfloat16*)out + (size_t)row*NCLS;
            #pragma unroll
            for (int c = 0; c < NCLS; c++) o[c] = __float2bfloat16(s[c]);
        } else {
            float* o = (float*)out + (size_t)row*NCLS;
            #pragma unroll
            for (int c = 0; c < NCLS; c++) o[c] = s[c];
        }
    }
}

extern "C" void kernel_launch(void* const* d_in, const int* in_sizes, int n_in,
                              void* d_out, int out_size, void* d_ws, size_t ws_size,
                              hipStream_t stream) {
    const void* x   = d_in[0];
    const void* W1  = d_in[1];
    const void* b1  = d_in[2];
    const void* W2  = d_in[3];
    const void* b2  = d_in[4];
    const void* W3  = d_in[5];
    const void* b3  = d_in[6];
    const void* Wli = d_in[7];
    float* ws = (float*)d_ws;
    const int batch = in_sizes[0] / FEAT;   // 4096

    prep_k<<<385, 256, 0, stream>>>(x, W1, W2, W3, Wli, b1, b2, b3, ws);
    snn_k<<<batch/4, 256, 0, stream>>>(x, ws, d_out);
}